// Round 1
// baseline (349.906 us; speedup 1.0000x reference)
//
#include <hip/hip_runtime.h>
#include <math.h>

#define NUSERS 100000
#define NITEMS 50000
#define NN (NUSERS + NITEMS)
#define EMB 64
#define NNZ_ 4000000
#define BB 4096
#define EPSN 1e-12f

// ws byte offsets
//  map  : int[NN]            @ 0        (600000 B, reserve 1 MiB)
//  acc  : float[2*BB*EMB]    @ 1 MiB    (2 MiB)
//  zu   : float[BB*EMB]      @ 3 MiB    (1 MiB)   normalized u rows
//  zi   : float[BB*EMB]      @ 4 MiB    (1 MiB)   normalized i rows
//  scal : float[8]           @ 5 MiB
//    scal[0]=align_sum scal[1]=reg_sum scal[2]=Seff_u scal[3]=Seff_i
//    scal[4]=Sdiag_u  scal[5]=Sdiag_i

__device__ inline float wave_reduce_sum(float v) {
  #pragma unroll
  for (int off = 32; off >= 1; off >>= 1) v += __shfl_xor(v, off, 64);
  return v;
}

__global__ __launch_bounds__(256) void lg_init(int* map, float* acc, float* scal) {
  int t = blockIdx.x * blockDim.x + threadIdx.x;
  if (t < NN) map[t] = -1;
  if (t < 2 * BB * EMB) acc[t] = 0.0f;
  if (t < 8) scal[t] = 0.0f;
}

__global__ __launch_bounds__(256) void lg_mark(const int* __restrict__ user,
                                               const int* __restrict__ positive,
                                               int* __restrict__ map) {
  int t = blockIdx.x * blockDim.x + threadIdx.x;
  if (t >= 2 * BB) return;
  int row = (t < BB) ? user[t] : (NUSERS + positive[t - BB]);
  atomicCAS(&map[row], -1, t);   // winner's t becomes the compact slot
}

// Scan all nnz; accumulate ax only for selected rows into acc[slot][*].
__global__ __launch_bounds__(256) void lg_scan(const int* __restrict__ rows,
                                               const int* __restrict__ cols,
                                               const float* __restrict__ vals,
                                               const int* __restrict__ map,
                                               const float* __restrict__ uemb,
                                               const float* __restrict__ iemb,
                                               float* __restrict__ acc) {
  int lane = threadIdx.x & 63;
  int w = (blockIdx.x * blockDim.x + threadIdx.x) >> 6;
  int nw = (gridDim.x * blockDim.x) >> 6;
  const int nchunk = NNZ_ / 64;
  for (int ch = w; ch < nchunk; ch += nw) {
    int k = ch * 64 + lane;
    int r = rows[k];
    int s = map[r];
    int c = cols[k];
    float v = vals[k];
    unsigned long long m = __ballot(s >= 0);
    while (m) {
      int j = __ffsll(m) - 1;
      m &= m - 1;
      int sj = __shfl(s, j, 64);
      int cj = __shfl(c, j, 64);
      float vj = __shfl(v, j, 64);
      const float* xr = (cj < NUSERS) ? (uemb + (size_t)cj * EMB)
                                      : (iemb + (size_t)(cj - NUSERS) * EMB);
      atomicAdd(&acc[(size_t)sj * EMB + lane], vj * xr[lane]);
    }
  }
}

// One wave per batch element: build z=2x+ax, normalize, store; accumulate
// align, reg, and exact diagonal Gram terms.
__global__ __launch_bounds__(256) void lg_prep(const int* __restrict__ user,
                                               const int* __restrict__ positive,
                                               const float* __restrict__ uemb,
                                               const float* __restrict__ iemb,
                                               const int* __restrict__ map,
                                               const float* __restrict__ acc,
                                               float* __restrict__ zu,
                                               float* __restrict__ zi,
                                               float* __restrict__ scal) {
  int w = (blockIdx.x * blockDim.x + threadIdx.x) >> 6;
  int lane = threadIdx.x & 63;
  if (w >= BB) return;
  int ru = user[w];
  int pi = positive[w];
  float eu = uemb[(size_t)ru * EMB + lane];
  float ei = iemb[(size_t)pi * EMB + lane];
  int su = map[ru];
  int si = map[NUSERS + pi];
  float zul = 2.0f * eu + acc[(size_t)su * EMB + lane];
  float zil = 2.0f * ei + acc[(size_t)si * EMB + lane];
  float nu = wave_reduce_sum(zul * zul);
  float ni = wave_reduce_sum(zil * zil);
  float un = zul * rsqrtf(nu + EPSN);
  float inn = zil * rsqrtf(ni + EPSN);
  zu[(size_t)w * EMB + lane] = un;
  zi[(size_t)w * EMB + lane] = inn;
  float d = un - inn;
  float align_b = wave_reduce_sum(d * d);
  float su2 = wave_reduce_sum(un * un);
  float si2 = wave_reduce_sum(inn * inn);
  float reg_b = wave_reduce_sum(eu * eu + ei * ei);
  if (lane == 0) {
    atomicAdd(&scal[0], align_b);
    atomicAdd(&scal[1], reg_b);
    atomicAdd(&scal[4], expf(-2.0f * fmaxf(2.0f - 2.0f * su2, 0.0f)));
    atomicAdd(&scal[5], expf(-2.0f * fmaxf(2.0f - 2.0f * si2, 0.0f)));
  }
}

// 64x64 tile of the Gram matrix; only jb>=ib tiles; off-diag weighted 2x.
__global__ __launch_bounds__(256) void lg_gram(const float* __restrict__ zu,
                                               const float* __restrict__ zi,
                                               float* __restrict__ scal) {
  int jb = blockIdx.x, ib = blockIdx.y, m = blockIdx.z;
  if (jb < ib) return;
  const float* xn = (m == 0) ? zu : zi;
  __shared__ float As[EMB][68];   // [k][row], pitch 68 floats (16B-aligned rows)
  __shared__ float Bs[EMB][68];
  __shared__ float wsum[4];
  int t = threadIdx.x;
  const float4* arow = (const float4*)(xn + (size_t)ib * 64 * EMB);
  const float4* brow = (const float4*)(xn + (size_t)jb * 64 * EMB);
  #pragma unroll
  for (int it = 0; it < 4; ++it) {
    int idx = it * 256 + t;    // 0..1023
    int row = idx >> 4;
    int c4 = idx & 15;
    float4 va = arow[row * 16 + c4];
    float4 vb = brow[row * 16 + c4];
    int k = c4 * 4;
    As[k][row] = va.x; As[k + 1][row] = va.y; As[k + 2][row] = va.z; As[k + 3][row] = va.w;
    Bs[k][row] = vb.x; Bs[k + 1][row] = vb.y; Bs[k + 2][row] = vb.z; Bs[k + 3][row] = vb.w;
  }
  __syncthreads();
  int tx = t & 15, ty = t >> 4;
  float accv[4][4] = {{0.0f}};
  #pragma unroll
  for (int k = 0; k < EMB; ++k) {
    float4 a = *(const float4*)&As[k][ty * 4];
    float4 b = *(const float4*)&Bs[k][tx * 4];
    float ar[4] = {a.x, a.y, a.z, a.w};
    float br[4] = {b.x, b.y, b.z, b.w};
    #pragma unroll
    for (int r = 0; r < 4; ++r)
      #pragma unroll
      for (int c = 0; c < 4; ++c)
        accv[r][c] = fmaf(ar[r], br[c], accv[r][c]);
  }
  float s = 0.0f;
  #pragma unroll
  for (int r = 0; r < 4; ++r)
    #pragma unroll
    for (int c = 0; c < 4; ++c) {
      float sq = fmaxf(2.0f - 2.0f * accv[r][c], 0.0f);
      s += __expf(-2.0f * sq);
    }
  s = wave_reduce_sum(s);
  if ((t & 63) == 0) wsum[t >> 6] = s;
  __syncthreads();
  if (t == 0) {
    float tot = wsum[0] + wsum[1] + wsum[2] + wsum[3];
    float wgt = (ib == jb) ? 1.0f : 2.0f;
    atomicAdd(&scal[2 + m], wgt * tot);
  }
}

__global__ void lg_final(const float* __restrict__ scal, float* __restrict__ out) {
  if (threadIdx.x == 0 && blockIdx.x == 0) {
    float align = scal[0] / (float)BB;
    float reg = 1e-4f * 0.5f * scal[1] / (float)BB;
    float npairs = (float)BB * (float)(BB - 1) * 0.5f;
    float tri_u = (scal[2] - scal[4]) * 0.5f;
    float tri_i = (scal[3] - scal[5]) * 0.5f;
    float Lu = logf(tri_u / npairs);
    float Li = logf(tri_i / npairs);
    out[0] = align;
    out[1] = 0.5f * (Lu + Li);   // GAMMA = 1
    out[2] = reg;
  }
}

extern "C" void kernel_launch(void* const* d_in, const int* in_sizes, int n_in,
                              void* d_out, int out_size, void* d_ws, size_t ws_size,
                              hipStream_t stream) {
  const int* user = (const int*)d_in[0];
  const int* positive = (const int*)d_in[1];
  // d_in[2] = negative (unused by the reference output)
  const int* adj_rows = (const int*)d_in[3];
  const int* adj_cols = (const int*)d_in[4];
  const float* adj_vals = (const float*)d_in[5];
  const float* uemb = (const float*)d_in[6];
  const float* iemb = (const float*)d_in[7];

  char* ws = (char*)d_ws;
  int* map = (int*)(ws);
  float* acc = (float*)(ws + (1u << 20));
  float* zu = (float*)(ws + (3u << 20));
  float* zi = (float*)(ws + (4u << 20));
  float* scal = (float*)(ws + (5u << 20));
  float* out = (float*)d_out;

  lg_init<<<dim3(2048), dim3(256), 0, stream>>>(map, acc, scal);
  lg_mark<<<dim3(32), dim3(256), 0, stream>>>(user, positive, map);
  lg_scan<<<dim3(2048), dim3(256), 0, stream>>>(adj_rows, adj_cols, adj_vals, map,
                                                uemb, iemb, acc);
  lg_prep<<<dim3(1024), dim3(256), 0, stream>>>(user, positive, uemb, iemb, map,
                                                acc, zu, zi, scal);
  lg_gram<<<dim3(64, 64, 2), dim3(256), 0, stream>>>(zu, zi, scal);
  lg_final<<<dim3(1), dim3(64), 0, stream>>>(scal, out);
}

// Round 2
// 133.760 us; speedup vs baseline: 2.6159x; 2.6159x over previous
//
#include <hip/hip_runtime.h>
#include <math.h>

#define NUSERS 100000
#define NITEMS 50000
#define NN (NUSERS + NITEMS)
#define EMB 64
#define NNZ_ 4000000
#define BB 4096
#define EPSN 1e-12f

// ws layout (bytes):
//  map        : int[NN]          @ 0        (600000 B, reserve 1 MiB)
//  acc        : float[2*BB*EMB]  @ 1 MiB    (2 MiB)
//  zu         : float[BB*EMB]    @ 3 MiB    (1 MiB)
//  zi         : float[BB*EMB]    @ 4 MiB    (1 MiB)
//  part_align : float[BB]        @ 5 MiB
//  part_reg   : float[BB]        @ 5 MiB + 16 KiB
//  gpart      : float[2*4096]    @ 5 MiB + 32 KiB   (per-tile Gram sums)

__device__ inline float wave_reduce_sum(float v) {
  #pragma unroll
  for (int off = 32; off >= 1; off >>= 1) v += __shfl_xor(v, off, 64);
  return v;
}

__global__ __launch_bounds__(256) void lg_init(int* map, float* acc) {
  int t = blockIdx.x * blockDim.x + threadIdx.x;
  if (t < NN) map[t] = -1;
  if (t < 2 * BB * EMB) acc[t] = 0.0f;
}

__global__ __launch_bounds__(256) void lg_mark(const int* __restrict__ user,
                                               const int* __restrict__ positive,
                                               int* __restrict__ map) {
  int t = blockIdx.x * blockDim.x + threadIdx.x;
  if (t >= 2 * BB) return;
  int row = (t < BB) ? user[t] : (NUSERS + positive[t - BB]);
  atomicCAS(&map[row], -1, t);   // winner's t becomes the compact slot
}

// Scan all nnz; accumulate ax only for selected rows into acc[slot][*].
__global__ __launch_bounds__(256) void lg_scan(const int* __restrict__ rows,
                                               const int* __restrict__ cols,
                                               const float* __restrict__ vals,
                                               const int* __restrict__ map,
                                               const float* __restrict__ uemb,
                                               const float* __restrict__ iemb,
                                               float* __restrict__ acc) {
  int lane = threadIdx.x & 63;
  int w = (blockIdx.x * blockDim.x + threadIdx.x) >> 6;
  int nw = (gridDim.x * blockDim.x) >> 6;
  const int nchunk = NNZ_ / 64;
  for (int ch = w; ch < nchunk; ch += nw) {
    int k = ch * 64 + lane;
    int r = rows[k];
    int s = map[r];
    int c = cols[k];
    float v = vals[k];
    unsigned long long m = __ballot(s >= 0);
    while (m) {
      int j = __ffsll(m) - 1;
      m &= m - 1;
      int sj = __shfl(s, j, 64);
      int cj = __shfl(c, j, 64);
      float vj = __shfl(v, j, 64);
      const float* xr = (cj < NUSERS) ? (uemb + (size_t)cj * EMB)
                                      : (iemb + (size_t)(cj - NUSERS) * EMB);
      atomicAdd(&acc[(size_t)sj * EMB + lane], vj * xr[lane]);
    }
  }
}

// One wave per batch element: z = 2x + ax, normalize, store; per-wave partials.
__global__ __launch_bounds__(256) void lg_prep(const int* __restrict__ user,
                                               const int* __restrict__ positive,
                                               const float* __restrict__ uemb,
                                               const float* __restrict__ iemb,
                                               const int* __restrict__ map,
                                               const float* __restrict__ acc,
                                               float* __restrict__ zu,
                                               float* __restrict__ zi,
                                               float* __restrict__ part_align,
                                               float* __restrict__ part_reg) {
  int w = (blockIdx.x * blockDim.x + threadIdx.x) >> 6;
  int lane = threadIdx.x & 63;
  if (w >= BB) return;
  int ru = user[w];
  int pi = positive[w];
  float eu = uemb[(size_t)ru * EMB + lane];
  float ei = iemb[(size_t)pi * EMB + lane];
  int su = map[ru];
  int si = map[NUSERS + pi];
  float zul = 2.0f * eu + acc[(size_t)su * EMB + lane];
  float zil = 2.0f * ei + acc[(size_t)si * EMB + lane];
  float nu = wave_reduce_sum(zul * zul);
  float ni = wave_reduce_sum(zil * zil);
  float un = zul * rsqrtf(nu + EPSN);
  float inn = zil * rsqrtf(ni + EPSN);
  zu[(size_t)w * EMB + lane] = un;
  zi[(size_t)w * EMB + lane] = inn;
  float d = un - inn;
  float align_b = wave_reduce_sum(d * d);
  float reg_b = wave_reduce_sum(eu * eu + ei * ei);
  if (lane == 0) {
    part_align[w] = align_b;
    part_reg[w] = reg_b;
  }
}

// 64x64 tile of the Gram matrix; jb>=ib only; off-diag weighted 2x.
// Writes per-block partial to gpart (no contended atomics).
__global__ __launch_bounds__(256) void lg_gram(const float* __restrict__ zu,
                                               const float* __restrict__ zi,
                                               float* __restrict__ gpart) {
  int jb = blockIdx.x, ib = blockIdx.y, m = blockIdx.z;
  int bid = m * 4096 + ib * 64 + jb;
  if (jb < ib) {
    if (threadIdx.x == 0) gpart[bid] = 0.0f;
    return;
  }
  const float* xn = (m == 0) ? zu : zi;
  __shared__ float As[EMB][68];
  __shared__ float Bs[EMB][68];
  __shared__ float wsum[4];
  int t = threadIdx.x;
  const float4* arow = (const float4*)(xn + (size_t)ib * 64 * EMB);
  const float4* brow = (const float4*)(xn + (size_t)jb * 64 * EMB);
  #pragma unroll
  for (int it = 0; it < 4; ++it) {
    int idx = it * 256 + t;    // 0..1023
    int row = idx >> 4;
    int c4 = idx & 15;
    float4 va = arow[row * 16 + c4];
    float4 vb = brow[row * 16 + c4];
    int k = c4 * 4;
    As[k][row] = va.x; As[k + 1][row] = va.y; As[k + 2][row] = va.z; As[k + 3][row] = va.w;
    Bs[k][row] = vb.x; Bs[k + 1][row] = vb.y; Bs[k + 2][row] = vb.z; Bs[k + 3][row] = vb.w;
  }
  __syncthreads();
  int tx = t & 15, ty = t >> 4;
  float accv[4][4] = {{0.0f}};
  #pragma unroll
  for (int k = 0; k < EMB; ++k) {
    float4 a = *(const float4*)&As[k][ty * 4];
    float4 b = *(const float4*)&Bs[k][tx * 4];
    float ar[4] = {a.x, a.y, a.z, a.w};
    float br[4] = {b.x, b.y, b.z, b.w};
    #pragma unroll
    for (int r = 0; r < 4; ++r)
      #pragma unroll
      for (int c = 0; c < 4; ++c)
        accv[r][c] = fmaf(ar[r], br[c], accv[r][c]);
  }
  float s = 0.0f;
  #pragma unroll
  for (int r = 0; r < 4; ++r)
    #pragma unroll
    for (int c = 0; c < 4; ++c) {
      float sq = fmaxf(2.0f - 2.0f * accv[r][c], 0.0f);
      s += __expf(-2.0f * sq);
    }
  s = wave_reduce_sum(s);
  if ((t & 63) == 0) wsum[t >> 6] = s;
  __syncthreads();
  if (t == 0) {
    float tot = wsum[0] + wsum[1] + wsum[2] + wsum[3];
    float wgt = (ib == jb) ? 1.0f : 2.0f;   // full-Gram sum via symmetry
    gpart[bid] = wgt * tot;
  }
}

// Single block: reduce all partials and emit the 3 outputs.
__global__ __launch_bounds__(256) void lg_final(const float* __restrict__ part_align,
                                                const float* __restrict__ part_reg,
                                                const float* __restrict__ gpart,
                                                float* __restrict__ out) {
  __shared__ float red[4][4];
  int t = threadIdx.x;
  float sa = 0.0f, sr = 0.0f, su = 0.0f, si = 0.0f;
  for (int k = t; k < 4096; k += 256) {
    sa += part_align[k];
    sr += part_reg[k];
    su += gpart[k];
    si += gpart[4096 + k];
  }
  sa = wave_reduce_sum(sa);
  sr = wave_reduce_sum(sr);
  su = wave_reduce_sum(su);
  si = wave_reduce_sum(si);
  if ((t & 63) == 0) {
    int wid = t >> 6;
    red[wid][0] = sa; red[wid][1] = sr; red[wid][2] = su; red[wid][3] = si;
  }
  __syncthreads();
  if (t == 0) {
    float a = 0, r = 0, Su = 0, Si = 0;
    #pragma unroll
    for (int wv = 0; wv < 4; ++wv) {
      a += red[wv][0]; r += red[wv][1]; Su += red[wv][2]; Si += red[wv][3];
    }
    float align = a / (float)BB;
    float reg = 1e-4f * 0.5f * r / (float)BB;
    float npairs = (float)BB * (float)(BB - 1) * 0.5f;
    // Normalized rows -> Gram diagonal == 1.0 (to fp32 rounding); diag sum = BB.
    float tri_u = (Su - (float)BB) * 0.5f;
    float tri_i = (Si - (float)BB) * 0.5f;
    float Lu = logf(tri_u / npairs);
    float Li = logf(tri_i / npairs);
    out[0] = align;
    out[1] = 0.5f * (Lu + Li);   // GAMMA = 1
    out[2] = reg;
  }
}

extern "C" void kernel_launch(void* const* d_in, const int* in_sizes, int n_in,
                              void* d_out, int out_size, void* d_ws, size_t ws_size,
                              hipStream_t stream) {
  const int* user = (const int*)d_in[0];
  const int* positive = (const int*)d_in[1];
  // d_in[2] = negative (unused by the reference output)
  const int* adj_rows = (const int*)d_in[3];
  const int* adj_cols = (const int*)d_in[4];
  const float* adj_vals = (const float*)d_in[5];
  const float* uemb = (const float*)d_in[6];
  const float* iemb = (const float*)d_in[7];

  char* ws = (char*)d_ws;
  int* map = (int*)(ws);
  float* acc = (float*)(ws + (1u << 20));
  float* zu = (float*)(ws + (3u << 20));
  float* zi = (float*)(ws + (4u << 20));
  float* part_align = (float*)(ws + (5u << 20));
  float* part_reg = (float*)(ws + (5u << 20) + (16u << 10));
  float* gpart = (float*)(ws + (5u << 20) + (32u << 10));
  float* out = (float*)d_out;

  lg_init<<<dim3(2048), dim3(256), 0, stream>>>(map, acc);
  lg_mark<<<dim3(32), dim3(256), 0, stream>>>(user, positive, map);
  lg_scan<<<dim3(2048), dim3(256), 0, stream>>>(adj_rows, adj_cols, adj_vals, map,
                                                uemb, iemb, acc);
  lg_prep<<<dim3(1024), dim3(256), 0, stream>>>(user, positive, uemb, iemb, map,
                                                acc, zu, zi, part_align, part_reg);
  lg_gram<<<dim3(64, 64, 2), dim3(256), 0, stream>>>(zu, zi, gpart);
  lg_final<<<dim3(1), dim3(256), 0, stream>>>(part_align, part_reg, gpart, out);
}

// Round 3
// 117.889 us; speedup vs baseline: 2.9681x; 1.1346x over previous
//
#include <hip/hip_runtime.h>
#include <math.h>

#define NUSERS 100000
#define NITEMS 50000
#define NN (NUSERS + NITEMS)
#define EMB 64
#define NNZ_ 4000000
#define BB 4096
#define NSLOT (2 * BB)
#define CAP 128
#define EPSN 1e-12f

// ws layout (bytes):
//  map        : int[NN]            @ 0        (600000 B, reserve 1 MiB)
//  fill       : int[NSLOT]         @ 1 MiB    (32 KiB)
//  bins       : uint2[NSLOT*CAP]   @ 2 MiB    (8 MiB)
//  acc        : float[NSLOT*EMB]   @ 10 MiB   (2 MiB)
//  zu         : float[BB*EMB]      @ 12 MiB   (1 MiB)
//  zi         : float[BB*EMB]      @ 13 MiB   (1 MiB)
//  part_align : float[BB]          @ 14 MiB
//  part_reg   : float[BB]          @ 14 MiB + 16 KiB
//  gpart      : float[2*4096]      @ 14 MiB + 32 KiB

__device__ inline float wave_reduce_sum(float v) {
  #pragma unroll
  for (int off = 32; off >= 1; off >>= 1) v += __shfl_xor(v, off, 64);
  return v;
}

__global__ __launch_bounds__(256) void lg_init(int* map, int* fill) {
  int t = blockIdx.x * blockDim.x + threadIdx.x;
  if (t < NN) map[t] = -1;
  if (t < NSLOT) fill[t] = 0;
}

__global__ __launch_bounds__(256) void lg_mark(const int* __restrict__ user,
                                               const int* __restrict__ positive,
                                               int* __restrict__ map) {
  int t = blockIdx.x * blockDim.x + threadIdx.x;
  if (t >= 2 * BB) return;
  int row = (t < BB) ? user[t] : (NUSERS + positive[t - BB]);
  atomicCAS(&map[row], -1, t);   // winner's t becomes the compact slot
}

__device__ inline void lg_bin_one(int r, int c, float v, const int* map,
                                  int* fill, uint2* bins) {
  int s = map[r];
  if (s >= 0) {
    int pos = atomicAdd(&fill[s], 1);
    if (pos < CAP) {
      uint2 e; e.x = (unsigned)c; e.y = __float_as_uint(v);
      bins[(size_t)s * CAP + pos] = e;
    }
  }
}

// Stream all nnz (int4/float4); hits drop {col,val} into per-slot bins.
__global__ __launch_bounds__(256) void lg_scan_bin(const int4* __restrict__ rows4,
                                                   const int4* __restrict__ cols4,
                                                   const float4* __restrict__ vals4,
                                                   const int* __restrict__ map,
                                                   int* __restrict__ fill,
                                                   uint2* __restrict__ bins) {
  int t = blockIdx.x * blockDim.x + threadIdx.x;
  if (t >= NNZ_ / 4) return;
  int4 r = rows4[t];
  int4 c = cols4[t];
  float4 v = vals4[t];
  lg_bin_one(r.x, c.x, v.x, map, fill, bins);
  lg_bin_one(r.y, c.y, v.y, map, fill, bins);
  lg_bin_one(r.z, c.z, v.z, map, fill, bins);
  lg_bin_one(r.w, c.w, v.w, map, fill, bins);
}

// One wave per slot: register-accumulate its bin entries, write acc once.
__global__ __launch_bounds__(256) void lg_accum(const int* __restrict__ fill,
                                                const uint2* __restrict__ bins,
                                                const float* __restrict__ uemb,
                                                const float* __restrict__ iemb,
                                                float* __restrict__ acc) {
  int w = (blockIdx.x * blockDim.x + threadIdx.x) >> 6;
  int lane = threadIdx.x & 63;
  if (w >= NSLOT) return;
  int n = min(fill[w], CAP);
  const uint2* bs = bins + (size_t)w * CAP;
  float a = 0.0f;
  int k = 0;
  for (; k + 2 <= n; k += 2) {
    uint2 e0 = bs[k];
    uint2 e1 = bs[k + 1];
    int c0 = (int)e0.x; float v0 = __uint_as_float(e0.y);
    int c1 = (int)e1.x; float v1 = __uint_as_float(e1.y);
    const float* x0 = (c0 < NUSERS) ? uemb + (size_t)c0 * EMB
                                    : iemb + (size_t)(c0 - NUSERS) * EMB;
    const float* x1 = (c1 < NUSERS) ? uemb + (size_t)c1 * EMB
                                    : iemb + (size_t)(c1 - NUSERS) * EMB;
    a = fmaf(v0, x0[lane], a);
    a = fmaf(v1, x1[lane], a);
  }
  if (k < n) {
    uint2 e0 = bs[k];
    int c0 = (int)e0.x; float v0 = __uint_as_float(e0.y);
    const float* x0 = (c0 < NUSERS) ? uemb + (size_t)c0 * EMB
                                    : iemb + (size_t)(c0 - NUSERS) * EMB;
    a = fmaf(v0, x0[lane], a);
  }
  acc[(size_t)w * EMB + lane] = a;
}

// One wave per batch element: z = 2x + ax, normalize, store; per-wave partials.
__global__ __launch_bounds__(256) void lg_prep(const int* __restrict__ user,
                                               const int* __restrict__ positive,
                                               const float* __restrict__ uemb,
                                               const float* __restrict__ iemb,
                                               const int* __restrict__ map,
                                               const float* __restrict__ acc,
                                               float* __restrict__ zu,
                                               float* __restrict__ zi,
                                               float* __restrict__ part_align,
                                               float* __restrict__ part_reg) {
  int w = (blockIdx.x * blockDim.x + threadIdx.x) >> 6;
  int lane = threadIdx.x & 63;
  if (w >= BB) return;
  int ru = user[w];
  int pi = positive[w];
  float eu = uemb[(size_t)ru * EMB + lane];
  float ei = iemb[(size_t)pi * EMB + lane];
  int su = map[ru];
  int si = map[NUSERS + pi];
  float zul = 2.0f * eu + acc[(size_t)su * EMB + lane];
  float zil = 2.0f * ei + acc[(size_t)si * EMB + lane];
  float nu = wave_reduce_sum(zul * zul);
  float ni = wave_reduce_sum(zil * zil);
  float un = zul * rsqrtf(nu + EPSN);
  float inn = zil * rsqrtf(ni + EPSN);
  zu[(size_t)w * EMB + lane] = un;
  zi[(size_t)w * EMB + lane] = inn;
  float d = un - inn;
  float align_b = wave_reduce_sum(d * d);
  float reg_b = wave_reduce_sum(eu * eu + ei * ei);
  if (lane == 0) {
    part_align[w] = align_b;
    part_reg[w] = reg_b;
  }
}

// 64x64 tile of the Gram matrix; jb>=ib only; off-diag weighted 2x.
__global__ __launch_bounds__(256) void lg_gram(const float* __restrict__ zu,
                                               const float* __restrict__ zi,
                                               float* __restrict__ gpart) {
  int jb = blockIdx.x, ib = blockIdx.y, m = blockIdx.z;
  int bid = m * 4096 + ib * 64 + jb;
  if (jb < ib) {
    if (threadIdx.x == 0) gpart[bid] = 0.0f;
    return;
  }
  const float* xn = (m == 0) ? zu : zi;
  __shared__ float As[EMB][68];
  __shared__ float Bs[EMB][68];
  __shared__ float wsum[4];
  int t = threadIdx.x;
  const float4* arow = (const float4*)(xn + (size_t)ib * 64 * EMB);
  const float4* brow = (const float4*)(xn + (size_t)jb * 64 * EMB);
  #pragma unroll
  for (int it = 0; it < 4; ++it) {
    int idx = it * 256 + t;    // 0..1023
    int row = idx >> 4;
    int c4 = idx & 15;
    float4 va = arow[row * 16 + c4];
    float4 vb = brow[row * 16 + c4];
    int k = c4 * 4;
    As[k][row] = va.x; As[k + 1][row] = va.y; As[k + 2][row] = va.z; As[k + 3][row] = va.w;
    Bs[k][row] = vb.x; Bs[k + 1][row] = vb.y; Bs[k + 2][row] = vb.z; Bs[k + 3][row] = vb.w;
  }
  __syncthreads();
  int tx = t & 15, ty = t >> 4;
  float accv[4][4] = {{0.0f}};
  #pragma unroll
  for (int k = 0; k < EMB; ++k) {
    float4 a = *(const float4*)&As[k][ty * 4];
    float4 b = *(const float4*)&Bs[k][tx * 4];
    float ar[4] = {a.x, a.y, a.z, a.w};
    float br[4] = {b.x, b.y, b.z, b.w};
    #pragma unroll
    for (int r = 0; r < 4; ++r)
      #pragma unroll
      for (int c = 0; c < 4; ++c)
        accv[r][c] = fmaf(ar[r], br[c], accv[r][c]);
  }
  float s = 0.0f;
  #pragma unroll
  for (int r = 0; r < 4; ++r)
    #pragma unroll
    for (int c = 0; c < 4; ++c) {
      float sq = fmaxf(2.0f - 2.0f * accv[r][c], 0.0f);
      s += __expf(-2.0f * sq);
    }
  s = wave_reduce_sum(s);
  if ((t & 63) == 0) wsum[t >> 6] = s;
  __syncthreads();
  if (t == 0) {
    float tot = wsum[0] + wsum[1] + wsum[2] + wsum[3];
    float wgt = (ib == jb) ? 1.0f : 2.0f;   // full-Gram sum via symmetry
    gpart[bid] = wgt * tot;
  }
}

// Single block: reduce all partials and emit the 3 outputs.
__global__ __launch_bounds__(256) void lg_final(const float* __restrict__ part_align,
                                                const float* __restrict__ part_reg,
                                                const float* __restrict__ gpart,
                                                float* __restrict__ out) {
  __shared__ float red[4][4];
  int t = threadIdx.x;
  float sa = 0.0f, sr = 0.0f, su = 0.0f, si = 0.0f;
  for (int k = t; k < 4096; k += 256) {
    sa += part_align[k];
    sr += part_reg[k];
    su += gpart[k];
    si += gpart[4096 + k];
  }
  sa = wave_reduce_sum(sa);
  sr = wave_reduce_sum(sr);
  su = wave_reduce_sum(su);
  si = wave_reduce_sum(si);
  if ((t & 63) == 0) {
    int wid = t >> 6;
    red[wid][0] = sa; red[wid][1] = sr; red[wid][2] = su; red[wid][3] = si;
  }
  __syncthreads();
  if (t == 0) {
    float a = 0, r = 0, Su = 0, Si = 0;
    #pragma unroll
    for (int wv = 0; wv < 4; ++wv) {
      a += red[wv][0]; r += red[wv][1]; Su += red[wv][2]; Si += red[wv][3];
    }
    float align = a / (float)BB;
    float reg = 1e-4f * 0.5f * r / (float)BB;
    float npairs = (float)BB * (float)(BB - 1) * 0.5f;
    // Normalized rows -> Gram diagonal == 1.0 (to fp32 rounding); diag sum = BB.
    float tri_u = (Su - (float)BB) * 0.5f;
    float tri_i = (Si - (float)BB) * 0.5f;
    float Lu = logf(tri_u / npairs);
    float Li = logf(tri_i / npairs);
    out[0] = align;
    out[1] = 0.5f * (Lu + Li);   // GAMMA = 1
    out[2] = reg;
  }
}

extern "C" void kernel_launch(void* const* d_in, const int* in_sizes, int n_in,
                              void* d_out, int out_size, void* d_ws, size_t ws_size,
                              hipStream_t stream) {
  const int* user = (const int*)d_in[0];
  const int* positive = (const int*)d_in[1];
  // d_in[2] = negative (unused by the reference output)
  const int* adj_rows = (const int*)d_in[3];
  const int* adj_cols = (const int*)d_in[4];
  const float* adj_vals = (const float*)d_in[5];
  const float* uemb = (const float*)d_in[6];
  const float* iemb = (const float*)d_in[7];

  char* ws = (char*)d_ws;
  int* map = (int*)(ws);
  int* fill = (int*)(ws + (1u << 20));
  uint2* bins = (uint2*)(ws + (2u << 20));
  float* acc = (float*)(ws + (10u << 20));
  float* zu = (float*)(ws + (12u << 20));
  float* zi = (float*)(ws + (13u << 20));
  float* part_align = (float*)(ws + (14u << 20));
  float* part_reg = (float*)(ws + (14u << 20) + (16u << 10));
  float* gpart = (float*)(ws + (14u << 20) + (32u << 10));
  float* out = (float*)d_out;

  lg_init<<<dim3((NN + 255) / 256), dim3(256), 0, stream>>>(map, fill);
  lg_mark<<<dim3(32), dim3(256), 0, stream>>>(user, positive, map);
  lg_scan_bin<<<dim3((NNZ_ / 4 + 255) / 256), dim3(256), 0, stream>>>(
      (const int4*)adj_rows, (const int4*)adj_cols, (const float4*)adj_vals,
      map, fill, bins);
  lg_accum<<<dim3(NSLOT / 4), dim3(256), 0, stream>>>(fill, bins, uemb, iemb, acc);
  lg_prep<<<dim3(1024), dim3(256), 0, stream>>>(user, positive, uemb, iemb, map,
                                                acc, zu, zi, part_align, part_reg);
  lg_gram<<<dim3(64, 64, 2), dim3(256), 0, stream>>>(zu, zi, gpart);
  lg_final<<<dim3(1), dim3(256), 0, stream>>>(part_align, part_reg, gpart, out);
}

// Round 4
// 85.524 us; speedup vs baseline: 4.0913x; 1.3784x over previous
//
#include <hip/hip_runtime.h>
#include <math.h>

#define NUSERS 100000
#define NITEMS 50000
#define NN (NUSERS + NITEMS)
#define EMB 64
#define NNZ_ 4000000
#define BB 4096
#define NSLOT (2 * BB)
#define CAP 128
#define EPSN 1e-12f
#define NT128 32           // 4096 / 128 tiles per side

// ws layout (bytes):
//  map        : int[NN]            @ 0        (reserve 1 MiB)
//  fill       : int[NSLOT]         @ 1 MiB
//  bins       : uint2[NSLOT*CAP]   @ 2 MiB    (8 MiB)
//  acc        : float[NSLOT*EMB]   @ 10 MiB   (2 MiB)
//  zub        : ushort[BB*EMB]     @ 12 MiB   (512 KiB)  bf16 normalized u
//  zib        : ushort[BB*EMB]     @ 12.5 MiB (512 KiB)  bf16 normalized i
//  part_align : float[BB]          @ 13 MiB
//  part_reg   : float[BB]          @ 13 MiB + 16 KiB
//  gpart      : float[2*1024]      @ 13 MiB + 32 KiB

typedef __attribute__((ext_vector_type(8))) short short8v;
typedef __attribute__((ext_vector_type(16))) float f32x16;

__device__ inline float wave_reduce_sum(float v) {
  #pragma unroll
  for (int off = 32; off >= 1; off >>= 1) v += __shfl_xor(v, off, 64);
  return v;
}

__device__ inline unsigned short f2bf(float f) {
  unsigned u = __float_as_uint(f);
  unsigned r = u + 0x7fffu + ((u >> 16) & 1u);   // round-to-nearest-even
  return (unsigned short)(r >> 16);
}

__global__ __launch_bounds__(256) void lg_init(int* map, int* fill) {
  int t = blockIdx.x * blockDim.x + threadIdx.x;
  if (t < NN) map[t] = -1;
  if (t < NSLOT) fill[t] = 0;
}

__global__ __launch_bounds__(256) void lg_mark(const int* __restrict__ user,
                                               const int* __restrict__ positive,
                                               int* __restrict__ map) {
  int t = blockIdx.x * blockDim.x + threadIdx.x;
  if (t >= 2 * BB) return;
  int row = (t < BB) ? user[t] : (NUSERS + positive[t - BB]);
  atomicCAS(&map[row], -1, t);
}

__device__ inline void lg_bin_one(int r, int c, float v, const int* map,
                                  int* fill, uint2* bins) {
  int s = map[r];
  if (s >= 0) {
    int pos = atomicAdd(&fill[s], 1);
    if (pos < CAP) {
      uint2 e; e.x = (unsigned)c; e.y = __float_as_uint(v);
      bins[(size_t)s * CAP + pos] = e;
    }
  }
}

__global__ __launch_bounds__(256) void lg_scan_bin(const int4* __restrict__ rows4,
                                                   const int4* __restrict__ cols4,
                                                   const float4* __restrict__ vals4,
                                                   const int* __restrict__ map,
                                                   int* __restrict__ fill,
                                                   uint2* __restrict__ bins) {
  int t = blockIdx.x * blockDim.x + threadIdx.x;
  if (t >= NNZ_ / 4) return;
  int4 r = rows4[t];
  int4 c = cols4[t];
  float4 v = vals4[t];
  lg_bin_one(r.x, c.x, v.x, map, fill, bins);
  lg_bin_one(r.y, c.y, v.y, map, fill, bins);
  lg_bin_one(r.z, c.z, v.z, map, fill, bins);
  lg_bin_one(r.w, c.w, v.w, map, fill, bins);
}

__global__ __launch_bounds__(256) void lg_accum(const int* __restrict__ fill,
                                                const uint2* __restrict__ bins,
                                                const float* __restrict__ uemb,
                                                const float* __restrict__ iemb,
                                                float* __restrict__ acc) {
  int w = (blockIdx.x * blockDim.x + threadIdx.x) >> 6;
  int lane = threadIdx.x & 63;
  if (w >= NSLOT) return;
  int n = min(fill[w], CAP);
  const uint2* bs = bins + (size_t)w * CAP;
  float a = 0.0f;
  int k = 0;
  for (; k + 2 <= n; k += 2) {
    uint2 e0 = bs[k];
    uint2 e1 = bs[k + 1];
    int c0 = (int)e0.x; float v0 = __uint_as_float(e0.y);
    int c1 = (int)e1.x; float v1 = __uint_as_float(e1.y);
    const float* x0 = (c0 < NUSERS) ? uemb + (size_t)c0 * EMB
                                    : iemb + (size_t)(c0 - NUSERS) * EMB;
    const float* x1 = (c1 < NUSERS) ? uemb + (size_t)c1 * EMB
                                    : iemb + (size_t)(c1 - NUSERS) * EMB;
    a = fmaf(v0, x0[lane], a);
    a = fmaf(v1, x1[lane], a);
  }
  if (k < n) {
    uint2 e0 = bs[k];
    int c0 = (int)e0.x; float v0 = __uint_as_float(e0.y);
    const float* x0 = (c0 < NUSERS) ? uemb + (size_t)c0 * EMB
                                    : iemb + (size_t)(c0 - NUSERS) * EMB;
    a = fmaf(v0, x0[lane], a);
  }
  acc[(size_t)w * EMB + lane] = a;
}

// One wave per batch element; store normalized rows as bf16 for the MFMA gram.
__global__ __launch_bounds__(256) void lg_prep(const int* __restrict__ user,
                                               const int* __restrict__ positive,
                                               const float* __restrict__ uemb,
                                               const float* __restrict__ iemb,
                                               const int* __restrict__ map,
                                               const float* __restrict__ acc,
                                               unsigned short* __restrict__ zub,
                                               unsigned short* __restrict__ zib,
                                               float* __restrict__ part_align,
                                               float* __restrict__ part_reg) {
  int w = (blockIdx.x * blockDim.x + threadIdx.x) >> 6;
  int lane = threadIdx.x & 63;
  if (w >= BB) return;
  int ru = user[w];
  int pi = positive[w];
  float eu = uemb[(size_t)ru * EMB + lane];
  float ei = iemb[(size_t)pi * EMB + lane];
  int su = map[ru];
  int si = map[NUSERS + pi];
  float zul = 2.0f * eu + acc[(size_t)su * EMB + lane];
  float zil = 2.0f * ei + acc[(size_t)si * EMB + lane];
  float nu = wave_reduce_sum(zul * zul);
  float ni = wave_reduce_sum(zil * zil);
  float un = zul * rsqrtf(nu + EPSN);
  float inn = zil * rsqrtf(ni + EPSN);
  zub[(size_t)w * EMB + lane] = f2bf(un);
  zib[(size_t)w * EMB + lane] = f2bf(inn);
  float d = un - inn;
  float align_b = wave_reduce_sum(d * d);
  float reg_b = wave_reduce_sum(eu * eu + ei * ei);
  if (lane == 0) {
    part_align[w] = align_b;
    part_reg[w] = reg_b;
  }
}

// MFMA gram: 128x128 tile per block (4 waves x 64x64 each via 2x2 of 32x32x16).
// Fragments loaded straight from global (bf16 matrix is L2-resident).
// A[row=l&31][k=(l>>5)*8+j] and B[col=l&31][k=...] have IDENTICAL addressing
// for C = Z Z^T, and the C/D element layout is irrelevant (we only reduce).
__global__ __launch_bounds__(256) void lg_gram_mfma(const unsigned short* __restrict__ zub,
                                                    const unsigned short* __restrict__ zib,
                                                    float* __restrict__ gpart) {
  int jb = blockIdx.x, ib = blockIdx.y, m = blockIdx.z;
  int bid = (m << 10) + (ib << 5) + jb;
  if (jb < ib) {
    if (threadIdx.x == 0) gpart[bid] = 0.0f;
    return;
  }
  const unsigned short* z = (m == 0) ? zub : zib;
  __shared__ float wsum[4];
  int t = threadIdx.x;
  int l = t & 63, w = t >> 6;
  int wr = w >> 1, wc = w & 1;
  int lr = l & 31;
  int koff = (l >> 5) * 8;
  const short8v* pa0 = (const short8v*)(z + (size_t)(ib * 128 + wr * 64 + lr) * EMB + koff);
  const short8v* pa1 = (const short8v*)(z + (size_t)(ib * 128 + wr * 64 + 32 + lr) * EMB + koff);
  const short8v* pb0 = (const short8v*)(z + (size_t)(jb * 128 + wc * 64 + lr) * EMB + koff);
  const short8v* pb1 = (const short8v*)(z + (size_t)(jb * 128 + wc * 64 + 32 + lr) * EMB + koff);
  f32x16 a00 = {}, a01 = {}, a10 = {}, a11 = {};
  #pragma unroll
  for (int ks = 0; ks < 4; ++ks) {
    short8v a0 = pa0[ks * 2];
    short8v a1 = pa1[ks * 2];
    short8v b0 = pb0[ks * 2];
    short8v b1 = pb1[ks * 2];
    a00 = __builtin_amdgcn_mfma_f32_32x32x16_bf16(a0, b0, a00, 0, 0, 0);
    a01 = __builtin_amdgcn_mfma_f32_32x32x16_bf16(a0, b1, a01, 0, 0, 0);
    a10 = __builtin_amdgcn_mfma_f32_32x32x16_bf16(a1, b0, a10, 0, 0, 0);
    a11 = __builtin_amdgcn_mfma_f32_32x32x16_bf16(a1, b1, a11, 0, 0, 0);
  }
  float s = 0.0f;
  #pragma unroll
  for (int e = 0; e < 16; ++e) {
    float v0 = a00[e], v1 = a01[e], v2 = a10[e], v3 = a11[e];
    s += __expf(-2.0f * fmaxf(fmaf(-2.0f, v0, 2.0f), 0.0f));
    s += __expf(-2.0f * fmaxf(fmaf(-2.0f, v1, 2.0f), 0.0f));
    s += __expf(-2.0f * fmaxf(fmaf(-2.0f, v2, 2.0f), 0.0f));
    s += __expf(-2.0f * fmaxf(fmaf(-2.0f, v3, 2.0f), 0.0f));
  }
  s = wave_reduce_sum(s);
  if (l == 0) wsum[w] = s;
  __syncthreads();
  if (t == 0) {
    float tot = wsum[0] + wsum[1] + wsum[2] + wsum[3];
    float wgt = (ib == jb) ? 1.0f : 2.0f;   // S_full = 2*S_tri + S_diag
    gpart[bid] = wgt * tot;
  }
}

__global__ __launch_bounds__(256) void lg_final(const float* __restrict__ part_align,
                                                const float* __restrict__ part_reg,
                                                const float* __restrict__ gpart,
                                                float* __restrict__ out) {
  __shared__ float red[4][4];
  int t = threadIdx.x;
  float sa = 0.0f, sr = 0.0f, su = 0.0f, si = 0.0f;
  for (int k = t; k < 4096; k += 256) {
    sa += part_align[k];
    sr += part_reg[k];
  }
  for (int k = t; k < 1024; k += 256) {
    su += gpart[k];
    si += gpart[1024 + k];
  }
  sa = wave_reduce_sum(sa);
  sr = wave_reduce_sum(sr);
  su = wave_reduce_sum(su);
  si = wave_reduce_sum(si);
  if ((t & 63) == 0) {
    int wid = t >> 6;
    red[wid][0] = sa; red[wid][1] = sr; red[wid][2] = su; red[wid][3] = si;
  }
  __syncthreads();
  if (t == 0) {
    float a = 0, r = 0, Su = 0, Si = 0;
    #pragma unroll
    for (int wv = 0; wv < 4; ++wv) {
      a += red[wv][0]; r += red[wv][1]; Su += red[wv][2]; Si += red[wv][3];
    }
    float align = a / (float)BB;
    float reg = 1e-4f * 0.5f * r / (float)BB;
    float npairs = (float)BB * (float)(BB - 1) * 0.5f;
    // Normalized rows -> Gram diagonal == 1; subtract BB, halve.
    float tri_u = (Su - (float)BB) * 0.5f;
    float tri_i = (Si - (float)BB) * 0.5f;
    float Lu = logf(tri_u / npairs);
    float Li = logf(tri_i / npairs);
    out[0] = align;
    out[1] = 0.5f * (Lu + Li);   // GAMMA = 1
    out[2] = reg;
  }
}

extern "C" void kernel_launch(void* const* d_in, const int* in_sizes, int n_in,
                              void* d_out, int out_size, void* d_ws, size_t ws_size,
                              hipStream_t stream) {
  const int* user = (const int*)d_in[0];
  const int* positive = (const int*)d_in[1];
  // d_in[2] = negative (unused by the reference output)
  const int* adj_rows = (const int*)d_in[3];
  const int* adj_cols = (const int*)d_in[4];
  const float* adj_vals = (const float*)d_in[5];
  const float* uemb = (const float*)d_in[6];
  const float* iemb = (const float*)d_in[7];

  char* ws = (char*)d_ws;
  int* map = (int*)(ws);
  int* fill = (int*)(ws + (1u << 20));
  uint2* bins = (uint2*)(ws + (2u << 20));
  float* acc = (float*)(ws + (10u << 20));
  unsigned short* zub = (unsigned short*)(ws + (12u << 20));
  unsigned short* zib = (unsigned short*)(ws + (12u << 20) + (512u << 10));
  float* part_align = (float*)(ws + (13u << 20));
  float* part_reg = (float*)(ws + (13u << 20) + (16u << 10));
  float* gpart = (float*)(ws + (13u << 20) + (32u << 10));
  float* out = (float*)d_out;

  lg_init<<<dim3((NN + 255) / 256), dim3(256), 0, stream>>>(map, fill);
  lg_mark<<<dim3(32), dim3(256), 0, stream>>>(user, positive, map);
  lg_scan_bin<<<dim3((NNZ_ / 4 + 255) / 256), dim3(256), 0, stream>>>(
      (const int4*)adj_rows, (const int4*)adj_cols, (const float4*)adj_vals,
      map, fill, bins);
  lg_accum<<<dim3(NSLOT / 4), dim3(256), 0, stream>>>(fill, bins, uemb, iemb, acc);
  lg_prep<<<dim3(1024), dim3(256), 0, stream>>>(user, positive, uemb, iemb, map,
                                                acc, zub, zib, part_align, part_reg);
  lg_gram_mfma<<<dim3(NT128, NT128, 2), dim3(256), 0, stream>>>(zub, zib, gpart);
  lg_final<<<dim3(1), dim3(256), 0, stream>>>(part_align, part_reg, gpart, out);
}

// Round 5
// 81.769 us; speedup vs baseline: 4.2792x; 1.0459x over previous
//
#include <hip/hip_runtime.h>
#include <math.h>

#define NUSERS 100000
#define NITEMS 50000
#define NN (NUSERS + NITEMS)
#define EMB 64
#define NNZ_ 4000000
#define BB 4096
#define NSLOT (2 * BB)
#define CAP 128
#define FSTR 32            // fill counter stride (ints) = 128 B -> 1 line/slot
#define EPSN 1e-12f
#define NT128 32           // 4096 / 128 tiles per side

// ws layout (bytes):
//  map        : int[NN]            @ 0        (reserve 1 MiB)
//  fillp      : int[NSLOT*FSTR]    @ 1 MiB    (1 MiB)
//  bins       : uint2[NSLOT*CAP]   @ 2 MiB    (8 MiB)
//  acc        : float[NSLOT*EMB]   @ 10 MiB   (2 MiB)
//  zub        : ushort[BB*EMB]     @ 12 MiB   (512 KiB)
//  zib        : ushort[BB*EMB]     @ 12.5 MiB (512 KiB)
//  part_align : float[BB]          @ 13 MiB
//  part_reg   : float[BB]          @ 13 MiB + 16 KiB
//  gpart      : float[2*1024]      @ 13 MiB + 32 KiB

typedef __attribute__((ext_vector_type(8))) short short8v;
typedef __attribute__((ext_vector_type(16))) float f32x16;

__device__ inline float wave_reduce_sum(float v) {
  #pragma unroll
  for (int off = 32; off >= 1; off >>= 1) v += __shfl_xor(v, off, 64);
  return v;
}

__device__ inline unsigned short f2bf(float f) {
  unsigned u = __float_as_uint(f);
  unsigned r = u + 0x7fffu + ((u >> 16) & 1u);
  return (unsigned short)(r >> 16);
}

__global__ __launch_bounds__(256) void lg_init(int* map, int* fillp) {
  int t = blockIdx.x * blockDim.x + threadIdx.x;
  if (t < NN) map[t] = -1;
  if (t < NSLOT * FSTR) fillp[t] = 0;
}

__global__ __launch_bounds__(256) void lg_mark(const int* __restrict__ user,
                                               const int* __restrict__ positive,
                                               int* __restrict__ map) {
  int t = blockIdx.x * blockDim.x + threadIdx.x;
  if (t >= 2 * BB) return;
  int row = (t < BB) ? user[t] : (NUSERS + positive[t - BB]);
  atomicCAS(&map[row], -1, t);
}

__device__ inline void lg_bin_one(int r, int c, float v, const int* map,
                                  int* fillp, uint2* bins) {
  int s = map[r];
  if (s >= 0) {
    int pos = atomicAdd(&fillp[s * FSTR], 1);   // one line per slot counter
    if (pos < CAP) {
      uint2 e; e.x = (unsigned)c; e.y = __float_as_uint(v);
      bins[(size_t)s * CAP + pos] = e;
    }
  }
}

__global__ __launch_bounds__(256) void lg_scan_bin(const int4* __restrict__ rows4,
                                                   const int4* __restrict__ cols4,
                                                   const float4* __restrict__ vals4,
                                                   const int* __restrict__ map,
                                                   int* __restrict__ fillp,
                                                   uint2* __restrict__ bins) {
  int t = blockIdx.x * blockDim.x + threadIdx.x;
  if (t >= NNZ_ / 4) return;
  int4 r = rows4[t];
  int4 c = cols4[t];
  float4 v = vals4[t];
  lg_bin_one(r.x, c.x, v.x, map, fillp, bins);
  lg_bin_one(r.y, c.y, v.y, map, fillp, bins);
  lg_bin_one(r.z, c.z, v.z, map, fillp, bins);
  lg_bin_one(r.w, c.w, v.w, map, fillp, bins);
}

__global__ __launch_bounds__(256) void lg_accum(const int* __restrict__ fillp,
                                                const uint2* __restrict__ bins,
                                                const float* __restrict__ uemb,
                                                const float* __restrict__ iemb,
                                                float* __restrict__ acc) {
  int w = (blockIdx.x * blockDim.x + threadIdx.x) >> 6;
  int lane = threadIdx.x & 63;
  if (w >= NSLOT) return;
  int n = min(fillp[w * FSTR], CAP);
  const uint2* bs = bins + (size_t)w * CAP;
  float a = 0.0f;
  int k = 0;
  for (; k + 4 <= n; k += 4) {
    uint2 e0 = bs[k];
    uint2 e1 = bs[k + 1];
    uint2 e2 = bs[k + 2];
    uint2 e3 = bs[k + 3];
    int c0 = (int)e0.x; float v0 = __uint_as_float(e0.y);
    int c1 = (int)e1.x; float v1 = __uint_as_float(e1.y);
    int c2 = (int)e2.x; float v2 = __uint_as_float(e2.y);
    int c3 = (int)e3.x; float v3 = __uint_as_float(e3.y);
    const float* x0 = (c0 < NUSERS) ? uemb + (size_t)c0 * EMB : iemb + (size_t)(c0 - NUSERS) * EMB;
    const float* x1 = (c1 < NUSERS) ? uemb + (size_t)c1 * EMB : iemb + (size_t)(c1 - NUSERS) * EMB;
    const float* x2 = (c2 < NUSERS) ? uemb + (size_t)c2 * EMB : iemb + (size_t)(c2 - NUSERS) * EMB;
    const float* x3 = (c3 < NUSERS) ? uemb + (size_t)c3 * EMB : iemb + (size_t)(c3 - NUSERS) * EMB;
    float f0 = x0[lane], f1 = x1[lane], f2 = x2[lane], f3 = x3[lane];
    a = fmaf(v0, f0, a);
    a = fmaf(v1, f1, a);
    a = fmaf(v2, f2, a);
    a = fmaf(v3, f3, a);
  }
  for (; k < n; ++k) {
    uint2 e0 = bs[k];
    int c0 = (int)e0.x; float v0 = __uint_as_float(e0.y);
    const float* x0 = (c0 < NUSERS) ? uemb + (size_t)c0 * EMB : iemb + (size_t)(c0 - NUSERS) * EMB;
    a = fmaf(v0, x0[lane], a);
  }
  acc[(size_t)w * EMB + lane] = a;
}

__global__ __launch_bounds__(256) void lg_prep(const int* __restrict__ user,
                                               const int* __restrict__ positive,
                                               const float* __restrict__ uemb,
                                               const float* __restrict__ iemb,
                                               const int* __restrict__ map,
                                               const float* __restrict__ acc,
                                               unsigned short* __restrict__ zub,
                                               unsigned short* __restrict__ zib,
                                               float* __restrict__ part_align,
                                               float* __restrict__ part_reg) {
  int w = (blockIdx.x * blockDim.x + threadIdx.x) >> 6;
  int lane = threadIdx.x & 63;
  if (w >= BB) return;
  int ru = user[w];
  int pi = positive[w];
  float eu = uemb[(size_t)ru * EMB + lane];
  float ei = iemb[(size_t)pi * EMB + lane];
  int su = map[ru];
  int si = map[NUSERS + pi];
  float zul = 2.0f * eu + acc[(size_t)su * EMB + lane];
  float zil = 2.0f * ei + acc[(size_t)si * EMB + lane];
  float nu = wave_reduce_sum(zul * zul);
  float ni = wave_reduce_sum(zil * zil);
  float un = zul * rsqrtf(nu + EPSN);
  float inn = zil * rsqrtf(ni + EPSN);
  zub[(size_t)w * EMB + lane] = f2bf(un);
  zib[(size_t)w * EMB + lane] = f2bf(inn);
  float d = un - inn;
  float align_b = wave_reduce_sum(d * d);
  float reg_b = wave_reduce_sum(eu * eu + ei * ei);
  if (lane == 0) {
    part_align[w] = align_b;
    part_reg[w] = reg_b;
  }
}

// MFMA gram: 128x128 tile per block (4 waves x 64x64 each via 2x2 of 32x32x16).
__global__ __launch_bounds__(256) void lg_gram_mfma(const unsigned short* __restrict__ zub,
                                                    const unsigned short* __restrict__ zib,
                                                    float* __restrict__ gpart) {
  int jb = blockIdx.x, ib = blockIdx.y, m = blockIdx.z;
  int bid = (m << 10) + (ib << 5) + jb;
  if (jb < ib) {
    if (threadIdx.x == 0) gpart[bid] = 0.0f;
    return;
  }
  const unsigned short* z = (m == 0) ? zub : zib;
  __shared__ float wsum[4];
  int t = threadIdx.x;
  int l = t & 63, w = t >> 6;
  int wr = w >> 1, wc = w & 1;
  int lr = l & 31;
  int koff = (l >> 5) * 8;
  const short8v* pa0 = (const short8v*)(z + (size_t)(ib * 128 + wr * 64 + lr) * EMB + koff);
  const short8v* pa1 = (const short8v*)(z + (size_t)(ib * 128 + wr * 64 + 32 + lr) * EMB + koff);
  const short8v* pb0 = (const short8v*)(z + (size_t)(jb * 128 + wc * 64 + lr) * EMB + koff);
  const short8v* pb1 = (const short8v*)(z + (size_t)(jb * 128 + wc * 64 + 32 + lr) * EMB + koff);
  f32x16 a00 = {}, a01 = {}, a10 = {}, a11 = {};
  #pragma unroll
  for (int ks = 0; ks < 4; ++ks) {
    short8v a0 = pa0[ks * 2];
    short8v a1 = pa1[ks * 2];
    short8v b0 = pb0[ks * 2];
    short8v b1 = pb1[ks * 2];
    a00 = __builtin_amdgcn_mfma_f32_32x32x16_bf16(a0, b0, a00, 0, 0, 0);
    a01 = __builtin_amdgcn_mfma_f32_32x32x16_bf16(a0, b1, a01, 0, 0, 0);
    a10 = __builtin_amdgcn_mfma_f32_32x32x16_bf16(a1, b0, a10, 0, 0, 0);
    a11 = __builtin_amdgcn_mfma_f32_32x32x16_bf16(a1, b1, a11, 0, 0, 0);
  }
  float s = 0.0f;
  #pragma unroll
  for (int e = 0; e < 16; ++e) {
    float v0 = a00[e], v1 = a01[e], v2 = a10[e], v3 = a11[e];
    s += __expf(-2.0f * fmaxf(fmaf(-2.0f, v0, 2.0f), 0.0f));
    s += __expf(-2.0f * fmaxf(fmaf(-2.0f, v1, 2.0f), 0.0f));
    s += __expf(-2.0f * fmaxf(fmaf(-2.0f, v2, 2.0f), 0.0f));
    s += __expf(-2.0f * fmaxf(fmaf(-2.0f, v3, 2.0f), 0.0f));
  }
  s = wave_reduce_sum(s);
  if (l == 0) wsum[w] = s;
  __syncthreads();
  if (t == 0) {
    float tot = wsum[0] + wsum[1] + wsum[2] + wsum[3];
    float wgt = (ib == jb) ? 1.0f : 2.0f;
    gpart[bid] = wgt * tot;
  }
}

__global__ __launch_bounds__(256) void lg_final(const float* __restrict__ part_align,
                                                const float* __restrict__ part_reg,
                                                const float* __restrict__ gpart,
                                                float* __restrict__ out) {
  __shared__ float red[4][4];
  int t = threadIdx.x;
  float sa = 0.0f, sr = 0.0f, su = 0.0f, si = 0.0f;
  for (int k = t; k < 4096; k += 256) {
    sa += part_align[k];
    sr += part_reg[k];
  }
  for (int k = t; k < 1024; k += 256) {
    su += gpart[k];
    si += gpart[1024 + k];
  }
  sa = wave_reduce_sum(sa);
  sr = wave_reduce_sum(sr);
  su = wave_reduce_sum(su);
  si = wave_reduce_sum(si);
  if ((t & 63) == 0) {
    int wid = t >> 6;
    red[wid][0] = sa; red[wid][1] = sr; red[wid][2] = su; red[wid][3] = si;
  }
  __syncthreads();
  if (t == 0) {
    float a = 0, r = 0, Su = 0, Si = 0;
    #pragma unroll
    for (int wv = 0; wv < 4; ++wv) {
      a += red[wv][0]; r += red[wv][1]; Su += red[wv][2]; Si += red[wv][3];
    }
    float align = a / (float)BB;
    float reg = 1e-4f * 0.5f * r / (float)BB;
    float npairs = (float)BB * (float)(BB - 1) * 0.5f;
    float tri_u = (Su - (float)BB) * 0.5f;
    float tri_i = (Si - (float)BB) * 0.5f;
    float Lu = logf(tri_u / npairs);
    float Li = logf(tri_i / npairs);
    out[0] = align;
    out[1] = 0.5f * (Lu + Li);
    out[2] = reg;
  }
}

extern "C" void kernel_launch(void* const* d_in, const int* in_sizes, int n_in,
                              void* d_out, int out_size, void* d_ws, size_t ws_size,
                              hipStream_t stream) {
  const int* user = (const int*)d_in[0];
  const int* positive = (const int*)d_in[1];
  const int* adj_rows = (const int*)d_in[3];
  const int* adj_cols = (const int*)d_in[4];
  const float* adj_vals = (const float*)d_in[5];
  const float* uemb = (const float*)d_in[6];
  const float* iemb = (const float*)d_in[7];

  char* ws = (char*)d_ws;
  int* map = (int*)(ws);
  int* fillp = (int*)(ws + (1u << 20));
  uint2* bins = (uint2*)(ws + (2u << 20));
  float* acc = (float*)(ws + (10u << 20));
  unsigned short* zub = (unsigned short*)(ws + (12u << 20));
  unsigned short* zib = (unsigned short*)(ws + (12u << 20) + (512u << 10));
  float* part_align = (float*)(ws + (13u << 20));
  float* part_reg = (float*)(ws + (13u << 20) + (16u << 10));
  float* gpart = (float*)(ws + (13u << 20) + (32u << 10));
  float* out = (float*)d_out;

  // grid covers max(NN, NSLOT*FSTR) = 262144 threads
  lg_init<<<dim3(1024), dim3(256), 0, stream>>>(map, fillp);
  lg_mark<<<dim3(32), dim3(256), 0, stream>>>(user, positive, map);
  lg_scan_bin<<<dim3((NNZ_ / 4 + 255) / 256), dim3(256), 0, stream>>>(
      (const int4*)adj_rows, (const int4*)adj_cols, (const float4*)adj_vals,
      map, fillp, bins);
  lg_accum<<<dim3(NSLOT / 4), dim3(256), 0, stream>>>(fillp, bins, uemb, iemb, acc);
  lg_prep<<<dim3(1024), dim3(256), 0, stream>>>(user, positive, uemb, iemb, map,
                                                acc, zub, zib, part_align, part_reg);
  lg_gram_mfma<<<dim3(NT128, NT128, 2), dim3(256), 0, stream>>>(zub, zib, gpart);
  lg_final<<<dim3(1), dim3(256), 0, stream>>>(part_align, part_reg, gpart, out);
}

// Round 6
// 71.785 us; speedup vs baseline: 4.8744x; 1.1391x over previous
//
#include <hip/hip_runtime.h>
#include <math.h>

#define NUSERS 100000
#define NITEMS 50000
#define NN (NUSERS + NITEMS)
#define EMB 64
#define NNZ_ 4000000
#define BB 4096
#define NSLOT (2 * BB)
#define CAP 128
#define FSTR 32            // fill counter stride (ints) = 128 B -> 1 line/slot
#define BMW 4688           // bitmap words: ceil(150000/32)
#define EPSN 1e-12f
#define NT128 32           // 4096 / 128 tiles per side

// ws layout (bytes):
//  map        : int[NN]            @ 0        (reserve 1 MiB)
//  fillp      : int[NSLOT*FSTR]    @ 1 MiB    (1 MiB)
//  bins       : uint2[NSLOT*CAP]   @ 2 MiB    (8 MiB)
//  acc        : float[NSLOT*EMB]   @ 10 MiB   (2 MiB)
//  zub        : ushort[BB*EMB]     @ 12 MiB   (512 KiB)
//  zib        : ushort[BB*EMB]     @ 12.5 MiB (512 KiB)
//  part_align : float[BB]          @ 13 MiB
//  part_reg   : float[BB]          @ 13 MiB + 16 KiB
//  gpart      : float[2*1024]      @ 13 MiB + 32 KiB
//  bitmap     : uint[BMW]          @ 13 MiB + 64 KiB

typedef __attribute__((ext_vector_type(8))) short short8v;
typedef __attribute__((ext_vector_type(16))) float f32x16;

__device__ inline float wave_reduce_sum(float v) {
  #pragma unroll
  for (int off = 32; off >= 1; off >>= 1) v += __shfl_xor(v, off, 64);
  return v;
}

__device__ inline unsigned short f2bf(float f) {
  unsigned u = __float_as_uint(f);
  unsigned r = u + 0x7fffu + ((u >> 16) & 1u);
  return (unsigned short)(r >> 16);
}

__global__ __launch_bounds__(256) void lg_init(int* map, int* fillp, unsigned* bitmap) {
  int t = blockIdx.x * blockDim.x + threadIdx.x;
  if (t < NN) map[t] = -1;
  if (t < NSLOT * FSTR) fillp[t] = 0;
  if (t < BMW) bitmap[t] = 0u;
}

__global__ __launch_bounds__(256) void lg_mark(const int* __restrict__ user,
                                               const int* __restrict__ positive,
                                               int* __restrict__ map,
                                               unsigned* __restrict__ bitmap) {
  int t = blockIdx.x * blockDim.x + threadIdx.x;
  if (t >= 2 * BB) return;
  int row = (t < BB) ? user[t] : (NUSERS + positive[t - BB]);
  atomicCAS(&map[row], -1, t);
  atomicOr(&bitmap[row >> 5], 1u << (row & 31));
}

__device__ inline void lg_bin_one(int r, int c, float v, const unsigned* bm,
                                  const int* map, int* fillp, uint2* bins) {
  if ((bm[r >> 5] >> (r & 31)) & 1u) {   // LDS probe — no global transaction
    int s = map[r];                      // global gather only for ~5.5% hits
    int pos = atomicAdd(&fillp[s * FSTR], 1);
    if (pos < CAP) {
      uint2 e; e.x = (unsigned)c; e.y = __float_as_uint(v);
      bins[(size_t)s * CAP + pos] = e;
    }
  }
}

__global__ __launch_bounds__(256) void lg_scan_bin(const int4* __restrict__ rows4,
                                                   const int4* __restrict__ cols4,
                                                   const float4* __restrict__ vals4,
                                                   const unsigned* __restrict__ bitmap,
                                                   const int* __restrict__ map,
                                                   int* __restrict__ fillp,
                                                   uint2* __restrict__ bins) {
  __shared__ unsigned bm[BMW];
  for (int i = threadIdx.x; i < BMW; i += 256) bm[i] = bitmap[i];
  __syncthreads();
  const int ngroups = NNZ_ / 4;
  for (int g = blockIdx.x * 256 + threadIdx.x; g < ngroups; g += gridDim.x * 256) {
    int4 r = rows4[g];
    int4 c = cols4[g];
    float4 v = vals4[g];
    lg_bin_one(r.x, c.x, v.x, bm, map, fillp, bins);
    lg_bin_one(r.y, c.y, v.y, bm, map, fillp, bins);
    lg_bin_one(r.z, c.z, v.z, bm, map, fillp, bins);
    lg_bin_one(r.w, c.w, v.w, bm, map, fillp, bins);
  }
}

__global__ __launch_bounds__(256) void lg_accum(const int* __restrict__ fillp,
                                                const uint2* __restrict__ bins,
                                                const float* __restrict__ uemb,
                                                const float* __restrict__ iemb,
                                                float* __restrict__ acc) {
  int w = (blockIdx.x * blockDim.x + threadIdx.x) >> 6;
  int lane = threadIdx.x & 63;
  if (w >= NSLOT) return;
  int n = min(fillp[w * FSTR], CAP);
  const uint2* bs = bins + (size_t)w * CAP;
  float a = 0.0f;
  int k = 0;
  for (; k + 4 <= n; k += 4) {
    uint2 e0 = bs[k];
    uint2 e1 = bs[k + 1];
    uint2 e2 = bs[k + 2];
    uint2 e3 = bs[k + 3];
    int c0 = (int)e0.x; float v0 = __uint_as_float(e0.y);
    int c1 = (int)e1.x; float v1 = __uint_as_float(e1.y);
    int c2 = (int)e2.x; float v2 = __uint_as_float(e2.y);
    int c3 = (int)e3.x; float v3 = __uint_as_float(e3.y);
    const float* x0 = (c0 < NUSERS) ? uemb + (size_t)c0 * EMB : iemb + (size_t)(c0 - NUSERS) * EMB;
    const float* x1 = (c1 < NUSERS) ? uemb + (size_t)c1 * EMB : iemb + (size_t)(c1 - NUSERS) * EMB;
    const float* x2 = (c2 < NUSERS) ? uemb + (size_t)c2 * EMB : iemb + (size_t)(c2 - NUSERS) * EMB;
    const float* x3 = (c3 < NUSERS) ? uemb + (size_t)c3 * EMB : iemb + (size_t)(c3 - NUSERS) * EMB;
    float f0 = x0[lane], f1 = x1[lane], f2 = x2[lane], f3 = x3[lane];
    a = fmaf(v0, f0, a);
    a = fmaf(v1, f1, a);
    a = fmaf(v2, f2, a);
    a = fmaf(v3, f3, a);
  }
  for (; k < n; ++k) {
    uint2 e0 = bs[k];
    int c0 = (int)e0.x; float v0 = __uint_as_float(e0.y);
    const float* x0 = (c0 < NUSERS) ? uemb + (size_t)c0 * EMB : iemb + (size_t)(c0 - NUSERS) * EMB;
    a = fmaf(v0, x0[lane], a);
  }
  acc[(size_t)w * EMB + lane] = a;
}

__global__ __launch_bounds__(256) void lg_prep(const int* __restrict__ user,
                                               const int* __restrict__ positive,
                                               const float* __restrict__ uemb,
                                               const float* __restrict__ iemb,
                                               const int* __restrict__ map,
                                               const float* __restrict__ acc,
                                               unsigned short* __restrict__ zub,
                                               unsigned short* __restrict__ zib,
                                               float* __restrict__ part_align,
                                               float* __restrict__ part_reg) {
  int w = (blockIdx.x * blockDim.x + threadIdx.x) >> 6;
  int lane = threadIdx.x & 63;
  if (w >= BB) return;
  int ru = user[w];
  int pi = positive[w];
  float eu = uemb[(size_t)ru * EMB + lane];
  float ei = iemb[(size_t)pi * EMB + lane];
  int su = map[ru];
  int si = map[NUSERS + pi];
  float zul = 2.0f * eu + acc[(size_t)su * EMB + lane];
  float zil = 2.0f * ei + acc[(size_t)si * EMB + lane];
  float nu = wave_reduce_sum(zul * zul);
  float ni = wave_reduce_sum(zil * zil);
  float un = zul * rsqrtf(nu + EPSN);
  float inn = zil * rsqrtf(ni + EPSN);
  zub[(size_t)w * EMB + lane] = f2bf(un);
  zib[(size_t)w * EMB + lane] = f2bf(inn);
  float d = un - inn;
  float align_b = wave_reduce_sum(d * d);
  float reg_b = wave_reduce_sum(eu * eu + ei * ei);
  if (lane == 0) {
    part_align[w] = align_b;
    part_reg[w] = reg_b;
  }
}

// MFMA gram: 128x128 tile per block (4 waves x 64x64 each via 2x2 of 32x32x16).
__global__ __launch_bounds__(256) void lg_gram_mfma(const unsigned short* __restrict__ zub,
                                                    const unsigned short* __restrict__ zib,
                                                    float* __restrict__ gpart) {
  int jb = blockIdx.x, ib = blockIdx.y, m = blockIdx.z;
  int bid = (m << 10) + (ib << 5) + jb;
  if (jb < ib) {
    if (threadIdx.x == 0) gpart[bid] = 0.0f;
    return;
  }
  const unsigned short* z = (m == 0) ? zub : zib;
  __shared__ float wsum[4];
  int t = threadIdx.x;
  int l = t & 63, w = t >> 6;
  int wr = w >> 1, wc = w & 1;
  int lr = l & 31;
  int koff = (l >> 5) * 8;
  const short8v* pa0 = (const short8v*)(z + (size_t)(ib * 128 + wr * 64 + lr) * EMB + koff);
  const short8v* pa1 = (const short8v*)(z + (size_t)(ib * 128 + wr * 64 + 32 + lr) * EMB + koff);
  const short8v* pb0 = (const short8v*)(z + (size_t)(jb * 128 + wc * 64 + lr) * EMB + koff);
  const short8v* pb1 = (const short8v*)(z + (size_t)(jb * 128 + wc * 64 + 32 + lr) * EMB + koff);
  f32x16 a00 = {}, a01 = {}, a10 = {}, a11 = {};
  #pragma unroll
  for (int ks = 0; ks < 4; ++ks) {
    short8v a0 = pa0[ks * 2];
    short8v a1 = pa1[ks * 2];
    short8v b0 = pb0[ks * 2];
    short8v b1 = pb1[ks * 2];
    a00 = __builtin_amdgcn_mfma_f32_32x32x16_bf16(a0, b0, a00, 0, 0, 0);
    a01 = __builtin_amdgcn_mfma_f32_32x32x16_bf16(a0, b1, a01, 0, 0, 0);
    a10 = __builtin_amdgcn_mfma_f32_32x32x16_bf16(a1, b0, a10, 0, 0, 0);
    a11 = __builtin_amdgcn_mfma_f32_32x32x16_bf16(a1, b1, a11, 0, 0, 0);
  }
  float s = 0.0f;
  #pragma unroll
  for (int e = 0; e < 16; ++e) {
    float v0 = a00[e], v1 = a01[e], v2 = a10[e], v3 = a11[e];
    s += __expf(-2.0f * fmaxf(fmaf(-2.0f, v0, 2.0f), 0.0f));
    s += __expf(-2.0f * fmaxf(fmaf(-2.0f, v1, 2.0f), 0.0f));
    s += __expf(-2.0f * fmaxf(fmaf(-2.0f, v2, 2.0f), 0.0f));
    s += __expf(-2.0f * fmaxf(fmaf(-2.0f, v3, 2.0f), 0.0f));
  }
  s = wave_reduce_sum(s);
  if (l == 0) wsum[w] = s;
  __syncthreads();
  if (t == 0) {
    float tot = wsum[0] + wsum[1] + wsum[2] + wsum[3];
    float wgt = (ib == jb) ? 1.0f : 2.0f;
    gpart[bid] = wgt * tot;
  }
}

__global__ __launch_bounds__(256) void lg_final(const float* __restrict__ part_align,
                                                const float* __restrict__ part_reg,
                                                const float* __restrict__ gpart,
                                                float* __restrict__ out) {
  __shared__ float red[4][4];
  int t = threadIdx.x;
  float sa = 0.0f, sr = 0.0f, su = 0.0f, si = 0.0f;
  for (int k = t; k < 4096; k += 256) {
    sa += part_align[k];
    sr += part_reg[k];
  }
  for (int k = t; k < 1024; k += 256) {
    su += gpart[k];
    si += gpart[1024 + k];
  }
  sa = wave_reduce_sum(sa);
  sr = wave_reduce_sum(sr);
  su = wave_reduce_sum(su);
  si = wave_reduce_sum(si);
  if ((t & 63) == 0) {
    int wid = t >> 6;
    red[wid][0] = sa; red[wid][1] = sr; red[wid][2] = su; red[wid][3] = si;
  }
  __syncthreads();
  if (t == 0) {
    float a = 0, r = 0, Su = 0, Si = 0;
    #pragma unroll
    for (int wv = 0; wv < 4; ++wv) {
      a += red[wv][0]; r += red[wv][1]; Su += red[wv][2]; Si += red[wv][3];
    }
    float align = a / (float)BB;
    float reg = 1e-4f * 0.5f * r / (float)BB;
    float npairs = (float)BB * (float)(BB - 1) * 0.5f;
    float tri_u = (Su - (float)BB) * 0.5f;
    float tri_i = (Si - (float)BB) * 0.5f;
    float Lu = logf(tri_u / npairs);
    float Li = logf(tri_i / npairs);
    out[0] = align;
    out[1] = 0.5f * (Lu + Li);
    out[2] = reg;
  }
}

extern "C" void kernel_launch(void* const* d_in, const int* in_sizes, int n_in,
                              void* d_out, int out_size, void* d_ws, size_t ws_size,
                              hipStream_t stream) {
  const int* user = (const int*)d_in[0];
  const int* positive = (const int*)d_in[1];
  const int* adj_rows = (const int*)d_in[3];
  const int* adj_cols = (const int*)d_in[4];
  const float* adj_vals = (const float*)d_in[5];
  const float* uemb = (const float*)d_in[6];
  const float* iemb = (const float*)d_in[7];

  char* ws = (char*)d_ws;
  int* map = (int*)(ws);
  int* fillp = (int*)(ws + (1u << 20));
  uint2* bins = (uint2*)(ws + (2u << 20));
  float* acc = (float*)(ws + (10u << 20));
  unsigned short* zub = (unsigned short*)(ws + (12u << 20));
  unsigned short* zib = (unsigned short*)(ws + (12u << 20) + (512u << 10));
  float* part_align = (float*)(ws + (13u << 20));
  float* part_reg = (float*)(ws + (13u << 20) + (16u << 10));
  float* gpart = (float*)(ws + (13u << 20) + (32u << 10));
  unsigned* bitmap = (unsigned*)(ws + (13u << 20) + (64u << 10));
  float* out = (float*)d_out;

  lg_init<<<dim3(1024), dim3(256), 0, stream>>>(map, fillp, bitmap);
  lg_mark<<<dim3(32), dim3(256), 0, stream>>>(user, positive, map, bitmap);
  lg_scan_bin<<<dim3(2048), dim3(256), 0, stream>>>(
      (const int4*)adj_rows, (const int4*)adj_cols, (const float4*)adj_vals,
      bitmap, map, fillp, bins);
  lg_accum<<<dim3(NSLOT / 4), dim3(256), 0, stream>>>(fillp, bins, uemb, iemb, acc);
  lg_prep<<<dim3(1024), dim3(256), 0, stream>>>(user, positive, uemb, iemb, map,
                                                acc, zub, zib, part_align, part_reg);
  lg_gram_mfma<<<dim3(NT128, NT128, 2), dim3(256), 0, stream>>>(zub, zib, gpart);
  lg_final<<<dim3(1), dim3(256), 0, stream>>>(part_align, part_reg, gpart, out);
}